// Round 18
// baseline (390.031 us; speedup 1.0000x reference)
//
#include <hip/hip_runtime.h>
#include <math.h>

#define NN 8192
#define DIM 128
#define NBLK 2048   // (q 0..127) x (p 0..15)
#define REPS 8

typedef short bf16x8 __attribute__((ext_vector_type(8)));
typedef float f32x4 __attribute__((ext_vector_type(4)));

__device__ inline unsigned short f2bf(float x) {
    unsigned u = __float_as_uint(x);
    unsigned r = u + 0x7FFFu + ((u >> 16) & 1u);  // RNE
    return (unsigned short)(r >> 16);
}
__device__ inline float bf2f(unsigned short h) {
    return __uint_as_float(((unsigned)h) << 16);
}

// ---------------------------------------------------------------------------
// Kernel 0: pack mapping into MFMA-fragment-order bf16 chunks (1KB/wave-load).
// ---------------------------------------------------------------------------
__global__ void pack_kernel(const float* __restrict__ m, unsigned short* __restrict__ buf2) {
    const int t = threadIdx.x, l = t & 63;
    const int W = blockIdx.x * 4 + (t >> 6);
    const int g = W >> 2, kq = W & 3;
    const int row = g * 16 + (l & 15);
    const int k0 = kq * 32 + (l >> 4) * 8;
    const float* src = m + (size_t)row * DIM + k0;
    float4 v0 = *reinterpret_cast<const float4*>(src);
    float4 v1 = *reinterpret_cast<const float4*>(src + 4);
    float f[8] = {v0.x, v0.y, v0.z, v0.w, v1.x, v1.y, v1.z, v1.w};
    union { ushort4 u4[2]; unsigned short us[8]; } o;
#pragma unroll
    for (int q = 0; q < 8; ++q) o.us[q] = f2bf(f[q]);
    unsigned short* dst = buf2 + (size_t)W * 512 + l * 8;
    *reinterpret_cast<ushort4*>(dst) = o.u4[0];
    *reinterpret_cast<ushort4*>(dst + 4) = o.u4[1];
}

// ---------------------------------------------------------------------------
// Kernel 1: exact fp32 row norms
// ---------------------------------------------------------------------------
__global__ void sq_kernel(const float* __restrict__ mapping, float* __restrict__ sq) {
    int i = blockIdx.x * blockDim.x + threadIdx.x;
    if (i < NN) {
        const float4* row = reinterpret_cast<const float4*>(mapping + (size_t)i * DIM);
        float s = 0.f;
#pragma unroll
        for (int q = 0; q < DIM / 4; ++q) {
            float4 v = row[q];
            s += v.x * v.x + v.y * v.y + v.z * v.z + v.w * v.w;
        }
        sq[i] = s;
    }
}

// ---------------------------------------------------------------------------
// Kernel 2: r16 producer/consumer (best, 68.6µs) — UNCHANGED real path.
// ---------------------------------------------------------------------------
__global__ __launch_bounds__(512, 6) void dist_kernel(const unsigned short* __restrict__ buf2,
                                                      const float* __restrict__ D,
                                                      const float* __restrict__ sq,
                                                      float* __restrict__ partials) {
    __shared__ __align__(16) char dtile[4][64 * 144];  // 4-slot ring
    __shared__ float wred[8];

    const int t = threadIdx.x, l = t & 63, w = t >> 6;
    const int b = blockIdx.x;
    const int q = b >> 4, p = b & 15;
    const int cj0 = q + p;
    float psum = 0.f;

    if (cj0 < 128) {
        const int nt = (128 - cj0 + 15) >> 4;
        const int l15 = l & 15, hi = l >> 4;
        const int colq = hi * 4;
        const int strip = w & 3;
        const int i_row = q * 64 + strip * 16 + l15;
        const int ldsoff = (strip * 16 + l15) * 144 + hi * 8;

        if (w < 4) {
            bf16x8 af[4];
#pragma unroll
            for (int kq = 0; kq < 4; ++kq)
                af[kq] = *(const bf16x8*)(buf2 + (size_t)((q * 4 + strip) * 4 + kq) * 512 + l * 8);
            const float sa = sq[i_row];

            for (int tt = 0; tt < nt; ++tt) {
                const int cj = cj0 + tt * 16;
                char* slot = &dtile[tt & 3][0];
#pragma unroll
                for (int s = 0; s < 4; ++s) {
                    bf16x8 bfr[4];
#pragma unroll
                    for (int kq = 0; kq < 4; ++kq)
                        bfr[kq] = *(const bf16x8*)(buf2 + (size_t)((cj * 4 + s) * 4 + kq) * 512 + l * 8);
                    f32x4 sb = *(const f32x4*)(sq + cj * 64 + s * 16 + colq);
                    f32x4 acc = {};
#pragma unroll
                    for (int kq = 0; kq < 4; ++kq)
                        acc = __builtin_amdgcn_mfma_f32_16x16x32_bf16(bfr[kq], af[kq], acc, 0, 0, 0);
                    ushort4 o;
                    unsigned short* op = (unsigned short*)&o;
#pragma unroll
                    for (int r = 0; r < 4; ++r) {
                        float d2 = fmaf(-2.f, acc[r], sa + sb[r]);
                        op[r] = f2bf(sqrtf(fmaxf(d2, 0.f)));
                    }
                    *reinterpret_cast<ushort4*>(slot + ldsoff + s * 32) = o;
                }
                if ((tt & 1) == 1 || tt == nt - 1) {
                    asm volatile("s_waitcnt lgkmcnt(0)" ::: "memory");
                    __builtin_amdgcn_sched_barrier(0);
                    __builtin_amdgcn_s_barrier();
                }
            }
        } else {
            const float* Drow = D + (size_t)i_row * NN;

            auto consume = [&](int tile, const f32x4(&dc)[4]) {
                const int cj = cj0 + tile * 16;
                const char* slot = &dtile[tile & 3][0];
                if (cj != q) {
#pragma unroll
                    for (int s = 0; s < 4; ++s) {
                        ushort4 o = *reinterpret_cast<const ushort4*>(slot + ldsoff + s * 32);
                        const unsigned short* op = (const unsigned short*)&o;
#pragma unroll
                        for (int r = 0; r < 4; ++r) {
                            float Dv = dc[s][r];
                            psum += __fdividef(fabsf(bf2f(op[r]) - Dv), Dv);
                        }
                    }
                } else {
#pragma unroll
                    for (int s = 0; s < 4; ++s) {
                        ushort4 o = *reinterpret_cast<const ushort4*>(slot + ldsoff + s * 32);
                        const unsigned short* op = (const unsigned short*)&o;
#pragma unroll
                        for (int r = 0; r < 4; ++r) {
                            const int j = cj * 64 + s * 16 + colq + r;
                            if (j > i_row) {
                                float Dv = dc[s][r];
                                psum += __fdividef(fabsf(bf2f(op[r]) - Dv), Dv);
                            }
                        }
                    }
                }
            };

            f32x4 dA[4], dB[4];
#pragma unroll
            for (int s = 0; s < 4; ++s)
                dA[s] = *(const f32x4*)(Drow + cj0 * 64 + s * 16 + colq);

            bool cur_a = true;
            for (int tt = 0; tt < nt; ++tt) {
                if ((tt & 1) == 0) __builtin_amdgcn_s_barrier();
                const int ncj = cj0 + (tt + 1) * 16;
                if (cur_a) {
                    if (tt + 1 < nt) {
#pragma unroll
                        for (int s = 0; s < 4; ++s)
                            dB[s] = *(const f32x4*)(Drow + ncj * 64 + s * 16 + colq);
                    }
                    consume(tt, dA);
                } else {
                    if (tt + 1 < nt) {
#pragma unroll
                        for (int s = 0; s < 4; ++s)
                            dA[s] = *(const f32x4*)(Drow + ncj * 64 + s * 16 + colq);
                    }
                    consume(tt, dB);
                }
                cur_a = !cur_a;
            }
        }
    }

    for (int off = 32; off > 0; off >>= 1) psum += __shfl_down(psum, off, 64);
    __syncthreads();
    if (l == 0) wred[w] = psum;
    __syncthreads();
    if (t == 0) {
        float s = 0.f;
#pragma unroll
        for (int k = 0; k < 8; ++k) s += wred[k];
        partials[b] = 2.f * s;
    }
}

// ---------------------------------------------------------------------------
// DIAG A: exact r13/r16 consumer D shape (16 rows x 64B per inst, stride-16
// tile triangle walk), pure loads, 8 reps, max occupancy. Visible in top-5
// WITH REAL COUNTERS (>=157us guaranteed: even at 6.3 TB/s it takes ~170us).
// ---------------------------------------------------------------------------
__global__ __launch_bounds__(256, 8) void diagA_kernel(const float* __restrict__ D,
                                                       float* __restrict__ dummy) {
    const int t = threadIdx.x, l = t & 63;
    const int W = blockIdx.x * 4 + (t >> 6);   // 0..8191
    const int q = W >> 6, p = (W >> 2) & 15, strip = W & 3;
    const int cj0 = q + p;
    f32x4 acc = {};
    if (cj0 < 128) {
        const int i_row = q * 64 + strip * 16 + (l & 15);
        const int colq = (l >> 4) * 4;
        const float* Drow = D + (size_t)i_row * NN;
#pragma unroll 1
        for (int rep = 0; rep < REPS; ++rep) {
            for (int cj = cj0; cj < 128; cj += 16) {
#pragma unroll
                for (int s = 0; s < 4; ++s)
                    acc += *(const f32x4*)(Drow + cj * 64 + s * 16 + colq);
            }
        }
    }
    float psum = acc[0] + acc[1] + acc[2] + acc[3];
    for (int off = 32; off > 0; off >>= 1) psum += __shfl_down(psum, off, 64);
    if (l == 0) dummy[W >> 6] = psum;   // one store per... keep live, deterministic
}

// ---------------------------------------------------------------------------
// DIAG B: whole-row contiguous sweep of the same triangle (1KB/inst, the
// fillBuffer shape). Wave W owns rows W and 8190-W (balanced). 8 reps.
// ---------------------------------------------------------------------------
__global__ __launch_bounds__(256, 8) void diagB_kernel(const float* __restrict__ D,
                                                       float* __restrict__ dummy) {
    const int t = threadIdx.x, l = t & 63;
    const int W = blockIdx.x * 4 + (t >> 6);   // 0..4095
    f32x4 acc = {};
#pragma unroll 1
    for (int rep = 0; rep < REPS; ++rep) {
#pragma unroll 1
        for (int h = 0; h < 2; ++h) {
            const int i = h ? (8190 - W) : W;
            const float* Drow = D + (size_t)i * NN;
            const int jst = (i + 1) & ~255;
            for (int j = jst + l * 4; j < NN; j += 256)
                acc += *(const f32x4*)(Drow + j);
        }
    }
    float psum = acc[0] + acc[1] + acc[2] + acc[3];
    for (int off = 32; off > 0; off >>= 1) psum += __shfl_down(psum, off, 64);
    if (l == 0) dummy[W] = psum;
}

// ---------------------------------------------------------------------------
// Kernel 3: deterministic final reduction
// ---------------------------------------------------------------------------
__global__ void reduce_kernel(const float* __restrict__ partials, float* __restrict__ out) {
    __shared__ double sm[256];
    const int t = threadIdx.x;
    double s = 0.0;
    for (int i = t; i < NBLK; i += 256) s += (double)partials[i];
    sm[t] = s;
    __syncthreads();
    for (int off = 128; off > 0; off >>= 1) {
        if (t < off) sm[t] += sm[t + off];
        __syncthreads();
    }
    if (t == 0) out[0] = (float)(sm[0] / ((double)NN * (double)NN - (double)NN));
}

// ---------------------------------------------------------------------------
extern "C" void kernel_launch(void* const* d_in, const int* in_sizes, int n_in,
                              void* d_out, int out_size, void* d_ws, size_t ws_size,
                              hipStream_t stream) {
    const float* mapping = (const float*)d_in[0];
    const float* D       = (const float*)d_in[1];
    float* out = (float*)d_out;

    unsigned short* buf2 = (unsigned short*)d_ws;        // 2 MiB
    float* sq            = (float*)(buf2 + NN * DIM);    // NN floats
    float* partials      = sq + NN;                      // NBLK floats
    float* dummyA        = partials + NBLK;              // 8192 floats
    float* dummyB        = dummyA + 8192;                // 4096 floats

    pack_kernel<<<512, 256, 0, stream>>>(mapping, buf2);
    sq_kernel<<<NN / 256, 256, 0, stream>>>(mapping, sq);
    dist_kernel<<<NBLK, 512, 0, stream>>>(buf2, D, sq, partials);
    reduce_kernel<<<1, 256, 0, stream>>>(partials, out);
    // ---- diagnostics: both sized to appear in top-5 with true counters ----
    diagA_kernel<<<2048, 256, 0, stream>>>(D, dummyA);
    diagB_kernel<<<1024, 256, 0, stream>>>(D, dummyB);
}

// Round 19
// 70.141 us; speedup vs baseline: 5.5607x; 5.5607x over previous
//
#include <hip/hip_runtime.h>
#include <math.h>

#define NN 8192
#define DIM 128
#define NBLK 2048   // (q 0..127) x (p 0..15)

typedef short bf16x8 __attribute__((ext_vector_type(8)));
typedef float f32x4 __attribute__((ext_vector_type(4)));

__device__ inline unsigned short f2bf(float x) {
    unsigned u = __float_as_uint(x);
    unsigned r = u + 0x7FFFu + ((u >> 16) & 1u);  // RNE
    return (unsigned short)(r >> 16);
}
__device__ inline float bf2f(unsigned short h) {
    return __uint_as_float(((unsigned)h) << 16);
}

// ---------------------------------------------------------------------------
// Kernel 0: pack mapping into MFMA-fragment-order bf16 chunks (1KB/wave-load).
// ---------------------------------------------------------------------------
__global__ void pack_kernel(const float* __restrict__ m, unsigned short* __restrict__ buf2) {
    const int t = threadIdx.x, l = t & 63;
    const int W = blockIdx.x * 4 + (t >> 6);
    const int g = W >> 2, kq = W & 3;
    const int row = g * 16 + (l & 15);
    const int k0 = kq * 32 + (l >> 4) * 8;
    const float* src = m + (size_t)row * DIM + k0;
    float4 v0 = *reinterpret_cast<const float4*>(src);
    float4 v1 = *reinterpret_cast<const float4*>(src + 4);
    float f[8] = {v0.x, v0.y, v0.z, v0.w, v1.x, v1.y, v1.z, v1.w};
    union { ushort4 u4[2]; unsigned short us[8]; } o;
#pragma unroll
    for (int q = 0; q < 8; ++q) o.us[q] = f2bf(f[q]);
    unsigned short* dst = buf2 + (size_t)W * 512 + l * 8;
    *reinterpret_cast<ushort4*>(dst) = o.u4[0];
    *reinterpret_cast<ushort4*>(dst + 4) = o.u4[1];
}

// ---------------------------------------------------------------------------
// Kernel 1: exact fp32 row norms
// ---------------------------------------------------------------------------
__global__ void sq_kernel(const float* __restrict__ mapping, float* __restrict__ sq) {
    int i = blockIdx.x * blockDim.x + threadIdx.x;
    if (i < NN) {
        const float4* row = reinterpret_cast<const float4*>(mapping + (size_t)i * DIM);
        float s = 0.f;
#pragma unroll
        for (int q = 0; q < DIM / 4; ++q) {
            float4 v = row[q];
            s += v.x * v.x + v.y * v.y + v.z * v.z + v.w * v.w;
        }
        sq[i] = s;
    }
}

// ---------------------------------------------------------------------------
// Kernel 2: r16 producer/consumer + 3-TILE-DEEP consumer D pipeline.
// diagA (r18) proved this D gather shape delivers 6.17 TB/s when ~8 tiles of
// loads are in flight; r16's consumer held only 1 tile (~300cy slack vs
// ~1000+cy loaded-HBM latency). Consumer now: fully-unrolled 8 steps, three
// named buffers D0/D1/D2 (static reg indexing), issue D(t+3) after consuming
// D(t) -> waits always have 8 newer D loads outstanding + 2-3 periods slack.
// Producer + barrier protocol byte-identical to r16 (proven).
// ---------------------------------------------------------------------------
__global__ __launch_bounds__(512, 6) void dist_kernel(const unsigned short* __restrict__ buf2,
                                                      const float* __restrict__ D,
                                                      const float* __restrict__ sq,
                                                      float* __restrict__ partials) {
    __shared__ __align__(16) char dtile[4][64 * 144];  // 4-slot ring
    __shared__ float wred[8];

    const int t = threadIdx.x, l = t & 63, w = t >> 6;
    const int b = blockIdx.x;
    const int q = b >> 4, p = b & 15;
    const int cj0 = q + p;
    float psum = 0.f;

    if (cj0 < 128) {
        const int nt = (128 - cj0 + 15) >> 4;   // 1..8
        const int l15 = l & 15, hi = l >> 4;
        const int colq = hi * 4;
        const int strip = w & 3;
        const int i_row = q * 64 + strip * 16 + l15;
        const int ldsoff = (strip * 16 + l15) * 144 + hi * 8;

        if (w < 4) {
            // ========================= PRODUCER (r16, unchanged) =========
            bf16x8 af[4];
#pragma unroll
            for (int kq = 0; kq < 4; ++kq)
                af[kq] = *(const bf16x8*)(buf2 + (size_t)((q * 4 + strip) * 4 + kq) * 512 + l * 8);
            const float sa = sq[i_row];

            for (int tt = 0; tt < nt; ++tt) {
                const int cj = cj0 + tt * 16;
                char* slot = &dtile[tt & 3][0];
#pragma unroll
                for (int s = 0; s < 4; ++s) {
                    bf16x8 bfr[4];
#pragma unroll
                    for (int kq = 0; kq < 4; ++kq)
                        bfr[kq] = *(const bf16x8*)(buf2 + (size_t)((cj * 4 + s) * 4 + kq) * 512 + l * 8);
                    f32x4 sb = *(const f32x4*)(sq + cj * 64 + s * 16 + colq);
                    f32x4 acc = {};
#pragma unroll
                    for (int kq = 0; kq < 4; ++kq)
                        acc = __builtin_amdgcn_mfma_f32_16x16x32_bf16(bfr[kq], af[kq], acc, 0, 0, 0);
                    ushort4 o;
                    unsigned short* op = (unsigned short*)&o;
#pragma unroll
                    for (int r = 0; r < 4; ++r) {
                        float d2 = fmaf(-2.f, acc[r], sa + sb[r]);
                        op[r] = f2bf(sqrtf(fmaxf(d2, 0.f)));
                    }
                    *reinterpret_cast<ushort4*>(slot + ldsoff + s * 32) = o;
                }
                if ((tt & 1) == 1 || tt == nt - 1) {
                    asm volatile("s_waitcnt lgkmcnt(0)" ::: "memory");
                    __builtin_amdgcn_sched_barrier(0);
                    __builtin_amdgcn_s_barrier();
                }
            }
        } else {
            // ================= CONSUMER: 3-deep D pipeline ================
            const float* Drow = D + (size_t)i_row * NN;

            f32x4 D0[4], D1[4], D2[4];

            auto issue = [&](f32x4(&buf)[4], int tile) {
                const int cj = cj0 + tile * 16;
#pragma unroll
                for (int s = 0; s < 4; ++s)
                    buf[s] = *(const f32x4*)(Drow + cj * 64 + s * 16 + colq);
            };
            auto consume = [&](int tile, const f32x4(&dc)[4]) {
                const int cj = cj0 + tile * 16;
                const char* slot = &dtile[tile & 3][0];
                if (cj != q) {
#pragma unroll
                    for (int s = 0; s < 4; ++s) {
                        ushort4 o = *reinterpret_cast<const ushort4*>(slot + ldsoff + s * 32);
                        const unsigned short* op = (const unsigned short*)&o;
#pragma unroll
                        for (int r = 0; r < 4; ++r) {
                            float Dv = dc[s][r];
                            psum += __fdividef(fabsf(bf2f(op[r]) - Dv), Dv);
                        }
                    }
                } else {
#pragma unroll
                    for (int s = 0; s < 4; ++s) {
                        ushort4 o = *reinterpret_cast<const ushort4*>(slot + ldsoff + s * 32);
                        const unsigned short* op = (const unsigned short*)&o;
#pragma unroll
                        for (int r = 0; r < 4; ++r) {
                            const int j = cj * 64 + s * 16 + colq + r;
                            if (j > i_row) {
                                float Dv = dc[s][r];
                                psum += __fdividef(fabsf(bf2f(op[r]) - Dv), Dv);
                            }
                        }
                    }
                }
            };

            // prologue: 3 tiles of D in flight before the first barrier
            issue(D0, 0);
            if (nt > 1) issue(D1, 1);
            if (nt > 2) issue(D2, 2);

#define STEP(TT, BUF)                                        \
            if (TT < nt) {                                   \
                if ((TT & 1) == 0) __builtin_amdgcn_s_barrier(); \
                consume(TT, BUF);                            \
                if (TT + 3 < nt) issue(BUF, TT + 3);         \
            }
            STEP(0, D0)
            STEP(1, D1)
            STEP(2, D2)
            STEP(3, D0)
            STEP(4, D1)
            STEP(5, D2)
            STEP(6, D0)
            STEP(7, D1)
#undef STEP
        }
    }

    // ---- deterministic block reduction (producers contribute 0) ----
    for (int off = 32; off > 0; off >>= 1) psum += __shfl_down(psum, off, 64);
    __syncthreads();
    if (l == 0) wred[w] = psum;
    __syncthreads();
    if (t == 0) {
        float s = 0.f;
#pragma unroll
        for (int k = 0; k < 8; ++k) s += wred[k];
        partials[b] = 2.f * s;
    }
}

// ---------------------------------------------------------------------------
// Kernel 3: deterministic final reduction
// ---------------------------------------------------------------------------
__global__ void reduce_kernel(const float* __restrict__ partials, float* __restrict__ out) {
    __shared__ double sm[256];
    const int t = threadIdx.x;
    double s = 0.0;
    for (int i = t; i < NBLK; i += 256) s += (double)partials[i];
    sm[t] = s;
    __syncthreads();
    for (int off = 128; off > 0; off >>= 1) {
        if (t < off) sm[t] += sm[t + off];
        __syncthreads();
    }
    if (t == 0) out[0] = (float)(sm[0] / ((double)NN * (double)NN - (double)NN));
}

// ---------------------------------------------------------------------------
extern "C" void kernel_launch(void* const* d_in, const int* in_sizes, int n_in,
                              void* d_out, int out_size, void* d_ws, size_t ws_size,
                              hipStream_t stream) {
    const float* mapping = (const float*)d_in[0];
    const float* D       = (const float*)d_in[1];
    float* out = (float*)d_out;

    unsigned short* buf2 = (unsigned short*)d_ws;        // 2 MiB
    float* sq            = (float*)(buf2 + NN * DIM);    // NN floats
    float* partials      = sq + NN;                      // NBLK floats

    pack_kernel<<<512, 256, 0, stream>>>(mapping, buf2);
    sq_kernel<<<NN / 256, 256, 0, stream>>>(mapping, sq);
    dist_kernel<<<NBLK, 512, 0, stream>>>(buf2, D, sq, partials);
    reduce_kernel<<<1, 256, 0, stream>>>(partials, out);
}

// Round 20
// 68.136 us; speedup vs baseline: 5.7243x; 1.0294x over previous
//
#include <hip/hip_runtime.h>
#include <math.h>

#define NN 8192
#define DIM 128
#define NBLK 1024   // (q 0..127) x (p 0..7), stride-8 tile walk

typedef short bf16x8 __attribute__((ext_vector_type(8)));
typedef float f32x4 __attribute__((ext_vector_type(4)));

__device__ inline unsigned short f2bf(float x) {
    unsigned u = __float_as_uint(x);
    unsigned r = u + 0x7FFFu + ((u >> 16) & 1u);  // RNE
    return (unsigned short)(r >> 16);
}
__device__ inline float bf2f(unsigned short h) {
    return __uint_as_float(((unsigned)h) << 16);
}

// ---------------------------------------------------------------------------
// Kernel 0: pack mapping into MFMA-fragment-order bf16 chunks (1KB/wave-load).
// ---------------------------------------------------------------------------
__global__ void pack_kernel(const float* __restrict__ m, unsigned short* __restrict__ buf2) {
    const int t = threadIdx.x, l = t & 63;
    const int W = blockIdx.x * 4 + (t >> 6);
    const int g = W >> 2, kq = W & 3;
    const int row = g * 16 + (l & 15);
    const int k0 = kq * 32 + (l >> 4) * 8;
    const float* src = m + (size_t)row * DIM + k0;
    float4 v0 = *reinterpret_cast<const float4*>(src);
    float4 v1 = *reinterpret_cast<const float4*>(src + 4);
    float f[8] = {v0.x, v0.y, v0.z, v0.w, v1.x, v1.y, v1.z, v1.w};
    union { ushort4 u4[2]; unsigned short us[8]; } o;
#pragma unroll
    for (int q = 0; q < 8; ++q) o.us[q] = f2bf(f[q]);
    unsigned short* dst = buf2 + (size_t)W * 512 + l * 8;
    *reinterpret_cast<ushort4*>(dst) = o.u4[0];
    *reinterpret_cast<ushort4*>(dst + 4) = o.u4[1];
}

// ---------------------------------------------------------------------------
// Kernel 1: exact fp32 row norms
// ---------------------------------------------------------------------------
__global__ void sq_kernel(const float* __restrict__ mapping, float* __restrict__ sq) {
    int i = blockIdx.x * blockDim.x + threadIdx.x;
    if (i < NN) {
        const float4* row = reinterpret_cast<const float4*>(mapping + (size_t)i * DIM);
        float s = 0.f;
#pragma unroll
        for (int q = 0; q < DIM / 4; ++q) {
            float4 v = row[q];
            s += v.x * v.x + v.y * v.y + v.z * v.z + v.w * v.w;
        }
        sq[i] = s;
    }
}

// ---------------------------------------------------------------------------
// Kernel 2: r16 producer/consumer with DOUBLED per-block work.
// Block (q,p): rows 64q..64q+63; tiles cj = q+p, +8, +16, .. (<128) —
// 1024 blocks x avg 8 tiles (was 2048 x 4.5): halves prologue/drain events
// and rendezvous warm-ups; the barrier pipeline runs twice as long in steady
// state. Producer, consumer, 4-slot ring, barrier-every-2-tiles protocol,
// (512,6) occupancy all byte-identical to r16 (best, 68.6us).
// Coverage: cj - q = p + 8k unique per (p,k); diagonal tile cj==q at p=0,k=0.
// ---------------------------------------------------------------------------
__global__ __launch_bounds__(512, 6) void dist_kernel(const unsigned short* __restrict__ buf2,
                                                      const float* __restrict__ D,
                                                      const float* __restrict__ sq,
                                                      float* __restrict__ partials) {
    __shared__ __align__(16) char dtile[4][64 * 144];  // 4-slot ring
    __shared__ float wred[8];

    const int t = threadIdx.x, l = t & 63, w = t >> 6;
    const int b = blockIdx.x;
    const int q = b >> 3, p = b & 7;
    const int cj0 = q + p;
    float psum = 0.f;

    if (cj0 < 128) {
        const int nt = ((127 - cj0) >> 3) + 1;   // 1..16
        const int l15 = l & 15, hi = l >> 4;
        const int colq = hi * 4;
        const int strip = w & 3;
        const int i_row = q * 64 + strip * 16 + l15;
        const int ldsoff = (strip * 16 + l15) * 144 + hi * 8;

        if (w < 4) {
            // ========================= PRODUCER =========================
            bf16x8 af[4];
#pragma unroll
            for (int kq = 0; kq < 4; ++kq)
                af[kq] = *(const bf16x8*)(buf2 + (size_t)((q * 4 + strip) * 4 + kq) * 512 + l * 8);
            const float sa = sq[i_row];

            for (int tt = 0; tt < nt; ++tt) {
                const int cj = cj0 + tt * 8;
                char* slot = &dtile[tt & 3][0];
#pragma unroll
                for (int s = 0; s < 4; ++s) {
                    bf16x8 bfr[4];
#pragma unroll
                    for (int kq = 0; kq < 4; ++kq)
                        bfr[kq] = *(const bf16x8*)(buf2 + (size_t)((cj * 4 + s) * 4 + kq) * 512 + l * 8);
                    f32x4 sb = *(const f32x4*)(sq + cj * 64 + s * 16 + colq);
                    f32x4 acc = {};
#pragma unroll
                    for (int kq = 0; kq < 4; ++kq)
                        acc = __builtin_amdgcn_mfma_f32_16x16x32_bf16(bfr[kq], af[kq], acc, 0, 0, 0);
                    ushort4 o;
                    unsigned short* op = (unsigned short*)&o;
#pragma unroll
                    for (int r = 0; r < 4; ++r) {
                        float d2 = fmaf(-2.f, acc[r], sa + sb[r]);
                        op[r] = f2bf(sqrtf(fmaxf(d2, 0.f)));
                    }
                    *reinterpret_cast<ushort4*>(slot + ldsoff + s * 32) = o;
                }
                if ((tt & 1) == 1 || tt == nt - 1) {
                    asm volatile("s_waitcnt lgkmcnt(0)" ::: "memory");
                    __builtin_amdgcn_sched_barrier(0);
                    __builtin_amdgcn_s_barrier();
                }
            }
        } else {
            // ========================= CONSUMER =========================
            const float* Drow = D + (size_t)i_row * NN;

            auto consume = [&](int tile, const f32x4(&dc)[4]) {
                const int cj = cj0 + tile * 8;
                const char* slot = &dtile[tile & 3][0];
                if (cj != q) {
#pragma unroll
                    for (int s = 0; s < 4; ++s) {
                        ushort4 o = *reinterpret_cast<const ushort4*>(slot + ldsoff + s * 32);
                        const unsigned short* op = (const unsigned short*)&o;
#pragma unroll
                        for (int r = 0; r < 4; ++r) {
                            float Dv = dc[s][r];
                            psum += __fdividef(fabsf(bf2f(op[r]) - Dv), Dv);
                        }
                    }
                } else {
#pragma unroll
                    for (int s = 0; s < 4; ++s) {
                        ushort4 o = *reinterpret_cast<const ushort4*>(slot + ldsoff + s * 32);
                        const unsigned short* op = (const unsigned short*)&o;
#pragma unroll
                        for (int r = 0; r < 4; ++r) {
                            const int j = cj * 64 + s * 16 + colq + r;
                            if (j > i_row) {
                                float Dv = dc[s][r];
                                psum += __fdividef(fabsf(bf2f(op[r]) - Dv), Dv);
                            }
                        }
                    }
                }
            };

            f32x4 dA[4], dB[4];
#pragma unroll
            for (int s = 0; s < 4; ++s)
                dA[s] = *(const f32x4*)(Drow + cj0 * 64 + s * 16 + colq);

            bool cur_a = true;
            for (int tt = 0; tt < nt; ++tt) {
                if ((tt & 1) == 0) __builtin_amdgcn_s_barrier();
                const int ncj = cj0 + (tt + 1) * 8;
                if (cur_a) {
                    if (tt + 1 < nt) {
#pragma unroll
                        for (int s = 0; s < 4; ++s)
                            dB[s] = *(const f32x4*)(Drow + ncj * 64 + s * 16 + colq);
                    }
                    consume(tt, dA);
                } else {
                    if (tt + 1 < nt) {
#pragma unroll
                        for (int s = 0; s < 4; ++s)
                            dA[s] = *(const f32x4*)(Drow + ncj * 64 + s * 16 + colq);
                    }
                    consume(tt, dB);
                }
                cur_a = !cur_a;
            }
        }
    }

    // ---- deterministic block reduction (producers contribute 0) ----
    for (int off = 32; off > 0; off >>= 1) psum += __shfl_down(psum, off, 64);
    __syncthreads();
    if (l == 0) wred[w] = psum;
    __syncthreads();
    if (t == 0) {
        float s = 0.f;
#pragma unroll
        for (int k = 0; k < 8; ++k) s += wred[k];
        partials[b] = 2.f * s;
    }
}

// ---------------------------------------------------------------------------
// Kernel 3: deterministic final reduction
// ---------------------------------------------------------------------------
__global__ void reduce_kernel(const float* __restrict__ partials, float* __restrict__ out) {
    __shared__ double sm[256];
    const int t = threadIdx.x;
    double s = 0.0;
    for (int i = t; i < NBLK; i += 256) s += (double)partials[i];
    sm[t] = s;
    __syncthreads();
    for (int off = 128; off > 0; off >>= 1) {
        if (t < off) sm[t] += sm[t + off];
        __syncthreads();
    }
    if (t == 0) out[0] = (float)(sm[0] / ((double)NN * (double)NN - (double)NN));
}

// ---------------------------------------------------------------------------
extern "C" void kernel_launch(void* const* d_in, const int* in_sizes, int n_in,
                              void* d_out, int out_size, void* d_ws, size_t ws_size,
                              hipStream_t stream) {
    const float* mapping = (const float*)d_in[0];
    const float* D       = (const float*)d_in[1];
    float* out = (float*)d_out;

    unsigned short* buf2 = (unsigned short*)d_ws;        // 2 MiB
    float* sq            = (float*)(buf2 + NN * DIM);    // NN floats
    float* partials      = sq + NN;                      // NBLK floats

    pack_kernel<<<512, 256, 0, stream>>>(mapping, buf2);
    sq_kernel<<<NN / 256, 256, 0, stream>>>(mapping, sq);
    dist_kernel<<<NBLK, 512, 0, stream>>>(buf2, D, sq, partials);
    reduce_kernel<<<1, 256, 0, stream>>>(partials, out);
}

// Round 21
// 65.941 us; speedup vs baseline: 5.9148x; 1.0333x over previous
//
#include <hip/hip_runtime.h>
#include <math.h>

#define NN 8192
#define DIM 128
#define NBLK 1024   // (q 0..127) x (p 0..7), stride-8 tile walk

typedef short bf16x8 __attribute__((ext_vector_type(8)));
typedef float f32x4 __attribute__((ext_vector_type(4)));

__device__ inline void gload_lds16(const void* g, void* l) {
    __builtin_amdgcn_global_load_lds((const __attribute__((address_space(1))) void*)g,
                                     (__attribute__((address_space(3))) void*)l, 16, 0, 0);
}

__device__ inline unsigned short f2bf(float x) {
    unsigned u = __float_as_uint(x);
    unsigned r = u + 0x7FFFu + ((u >> 16) & 1u);  // RNE
    return (unsigned short)(r >> 16);
}
__device__ inline float bf2f(unsigned short h) {
    return __uint_as_float(((unsigned)h) << 16);
}

// ---------------------------------------------------------------------------
// Kernel 0: pack mapping into MFMA-fragment-order bf16 chunks (1KB/wave-load).
// ---------------------------------------------------------------------------
__global__ void pack_kernel(const float* __restrict__ m, unsigned short* __restrict__ buf2) {
    const int t = threadIdx.x, l = t & 63;
    const int W = blockIdx.x * 4 + (t >> 6);
    const int g = W >> 2, kq = W & 3;
    const int row = g * 16 + (l & 15);
    const int k0 = kq * 32 + (l >> 4) * 8;
    const float* src = m + (size_t)row * DIM + k0;
    float4 v0 = *reinterpret_cast<const float4*>(src);
    float4 v1 = *reinterpret_cast<const float4*>(src + 4);
    float f[8] = {v0.x, v0.y, v0.z, v0.w, v1.x, v1.y, v1.z, v1.w};
    union { ushort4 u4[2]; unsigned short us[8]; } o;
#pragma unroll
    for (int q = 0; q < 8; ++q) o.us[q] = f2bf(f[q]);
    unsigned short* dst = buf2 + (size_t)W * 512 + l * 8;
    *reinterpret_cast<ushort4*>(dst) = o.u4[0];
    *reinterpret_cast<ushort4*>(dst + 4) = o.u4[1];
}

// ---------------------------------------------------------------------------
// Kernel 1: exact fp32 row norms
// ---------------------------------------------------------------------------
__global__ void sq_kernel(const float* __restrict__ mapping, float* __restrict__ sq) {
    int i = blockIdx.x * blockDim.x + threadIdx.x;
    if (i < NN) {
        const float4* row = reinterpret_cast<const float4*>(mapping + (size_t)i * DIM);
        float s = 0.f;
#pragma unroll
        for (int q = 0; q < DIM / 4; ++q) {
            float4 v = row[q];
            s += v.x * v.x + v.y * v.y + v.z * v.z + v.w * v.w;
        }
        sq[i] = s;
    }
}

// ---------------------------------------------------------------------------
// Kernel 2: r20 P/C + B STAGED ONCE PER BLOCK (global_load_lds, dbuf LDS).
// Producer wave w stages only col-subtile s=w (4x1KB) -> 16KB B-tile staged
// once instead of 4 waves x 16KB redundant reads: B traffic 528->132 MB.
// Producers ds_read fragments (lane*16 b128, conflict-free); consumers are
// byte-identical to r20 (pure-D FIFO, 1-deep double buffer).
// Barrier-per-tile (r13 protocol, proven == r16): producer 1+nt barriers,
// consumer 1+nt; dtile slot tt&1 written in tile tt, read in tt+1 (disjoint);
// Bbuf slot (tt+1)&1 staged in tile tt, ds_read in tt+1 (disjoint).
// ---------------------------------------------------------------------------
__global__ __launch_bounds__(512, 6) void dist_kernel(const unsigned short* __restrict__ buf2,
                                                      const float* __restrict__ D,
                                                      const float* __restrict__ sq,
                                                      float* __restrict__ partials) {
    __shared__ __align__(16) char Bbuf[2][16384];      // 32 KB
    __shared__ __align__(16) char dtile[2][64 * 144];  // 18.4 KB
    __shared__ float wred[8];

    const int t = threadIdx.x, l = t & 63, w = t >> 6;
    const int b = blockIdx.x;
    const int q = b >> 3, p = b & 7;
    const int cj0 = q + p;
    float psum = 0.f;

    if (cj0 < 128) {
        const int nt = ((127 - cj0) >> 3) + 1;   // 1..16
        const int l15 = l & 15, hi = l >> 4;
        const int colq = hi * 4;
        const int strip = w & 3;
        const int i_row = q * 64 + strip * 16 + l15;
        const int ldsoff = (strip * 16 + l15) * 144 + hi * 8;

        if (w < 4) {
            // ========================= PRODUCER =========================
            bf16x8 af[4];
#pragma unroll
            for (int kq = 0; kq < 4; ++kq)
                af[kq] = *(const bf16x8*)(buf2 + (size_t)((q * 4 + strip) * 4 + kq) * 512 + l * 8);
            const float sa = sq[i_row];

            f32x4 csb[4], nsb[4];
#pragma unroll
            for (int s = 0; s < 4; ++s)
                csb[s] = *(const f32x4*)(sq + cj0 * 64 + s * 16 + colq);
            // stage B(0) -> Bbuf[0]: wave w stages its col-subtile (4 chunks)
#pragma unroll
            for (int kq = 0; kq < 4; ++kq)
                gload_lds16(buf2 + (size_t)((cj0 * 4 + strip) * 4 + kq) * 512 + l * 8,
                            (void*)&Bbuf[0][(strip * 4 + kq) * 1024]);
            asm volatile("s_waitcnt vmcnt(0)" ::: "memory");
            __builtin_amdgcn_s_barrier();   // #0

            for (int tt = 0; tt < nt; ++tt) {
                const int slot = tt & 1;
                if (tt + 1 < nt) {
                    const int ncj = cj0 + (tt + 1) * 8;
#pragma unroll
                    for (int s = 0; s < 4; ++s)
                        nsb[s] = *(const f32x4*)(sq + ncj * 64 + s * 16 + colq);
#pragma unroll
                    for (int kq = 0; kq < 4; ++kq)
                        gload_lds16(buf2 + (size_t)((ncj * 4 + strip) * 4 + kq) * 512 + l * 8,
                                    (void*)&Bbuf[slot ^ 1][(strip * 4 + kq) * 1024]);
                }
                // compute tile tt from Bbuf[slot] (ds_read, conflict-free)
#pragma unroll
                for (int s = 0; s < 4; ++s) {
                    bf16x8 bfr[4];
#pragma unroll
                    for (int kq = 0; kq < 4; ++kq)
                        bfr[kq] = *(const bf16x8*)&Bbuf[slot][(s * 4 + kq) * 1024 + l * 16];
                    f32x4 acc = {};
#pragma unroll
                    for (int kq = 0; kq < 4; ++kq)
                        acc = __builtin_amdgcn_mfma_f32_16x16x32_bf16(bfr[kq], af[kq], acc, 0, 0, 0);
                    ushort4 o;
                    unsigned short* op = (unsigned short*)&o;
#pragma unroll
                    for (int r = 0; r < 4; ++r) {
                        float d2 = fmaf(-2.f, acc[r], sa + csb[s][r]);
                        op[r] = f2bf(sqrtf(fmaxf(d2, 0.f)));
                    }
                    *reinterpret_cast<ushort4*>(&dtile[slot][0] + ldsoff + s * 32) = o;
                }
                asm volatile("s_waitcnt vmcnt(0) lgkmcnt(0)" ::: "memory");
                __builtin_amdgcn_sched_barrier(0);
                __builtin_amdgcn_s_barrier();   // #tt+1
                if (tt + 1 < nt) {
#pragma unroll
                    for (int s = 0; s < 4; ++s) csb[s] = nsb[s];
                }
            }
        } else {
            // ========================= CONSUMER (r20, reindexed) =========
            const float* Drow = D + (size_t)i_row * NN;

            auto consume = [&](int tile, const f32x4(&dc)[4]) {
                const int cj = cj0 + tile * 8;
                const char* slot = &dtile[tile & 1][0];
                if (cj != q) {
#pragma unroll
                    for (int s = 0; s < 4; ++s) {
                        ushort4 o = *reinterpret_cast<const ushort4*>(slot + ldsoff + s * 32);
                        const unsigned short* op = (const unsigned short*)&o;
#pragma unroll
                        for (int r = 0; r < 4; ++r) {
                            float Dv = dc[s][r];
                            psum += __fdividef(fabsf(bf2f(op[r]) - Dv), Dv);
                        }
                    }
                } else {
#pragma unroll
                    for (int s = 0; s < 4; ++s) {
                        ushort4 o = *reinterpret_cast<const ushort4*>(slot + ldsoff + s * 32);
                        const unsigned short* op = (const unsigned short*)&o;
#pragma unroll
                        for (int r = 0; r < 4; ++r) {
                            const int j = cj * 64 + s * 16 + colq + r;
                            if (j > i_row) {
                                float Dv = dc[s][r];
                                psum += __fdividef(fabsf(bf2f(op[r]) - Dv), Dv);
                            }
                        }
                    }
                }
            };

            f32x4 dA[4], dB[4];
#pragma unroll
            for (int s = 0; s < 4; ++s)
                dA[s] = *(const f32x4*)(Drow + cj0 * 64 + s * 16 + colq);
            __builtin_amdgcn_s_barrier();   // #0

            bool cur_a = true;
            for (int tt = 0; tt < nt; ++tt) {
                if (tt + 1 < nt) {
                    const int ncj = cj0 + (tt + 1) * 8;
                    if (cur_a) {
#pragma unroll
                        for (int s = 0; s < 4; ++s)
                            dB[s] = *(const f32x4*)(Drow + ncj * 64 + s * 16 + colq);
                    } else {
#pragma unroll
                        for (int s = 0; s < 4; ++s)
                            dA[s] = *(const f32x4*)(Drow + ncj * 64 + s * 16 + colq);
                    }
                }
                __builtin_amdgcn_s_barrier();   // #tt+1: dtile(tt) ready
                if (cur_a) consume(tt, dA);
                else       consume(tt, dB);
                cur_a = !cur_a;
            }
        }
    }

    // ---- deterministic block reduction (producers contribute 0) ----
    for (int off = 32; off > 0; off >>= 1) psum += __shfl_down(psum, off, 64);
    __syncthreads();
    if (l == 0) wred[w] = psum;
    __syncthreads();
    if (t == 0) {
        float s = 0.f;
#pragma unroll
        for (int k = 0; k < 8; ++k) s += wred[k];
        partials[b] = 2.f * s;
    }
}

// ---------------------------------------------------------------------------
// Kernel 3: deterministic final reduction
// ---------------------------------------------------------------------------
__global__ void reduce_kernel(const float* __restrict__ partials, float* __restrict__ out) {
    __shared__ double sm[256];
    const int t = threadIdx.x;
    double s = 0.0;
    for (int i = t; i < NBLK; i += 256) s += (double)partials[i];
    sm[t] = s;
    __syncthreads();
    for (int off = 128; off > 0; off >>= 1) {
        if (t < off) sm[t] += sm[t + off];
        __syncthreads();
    }
    if (t == 0) out[0] = (float)(sm[0] / ((double)NN * (double)NN - (double)NN));
}

// ---------------------------------------------------------------------------
extern "C" void kernel_launch(void* const* d_in, const int* in_sizes, int n_in,
                              void* d_out, int out_size, void* d_ws, size_t ws_size,
                              hipStream_t stream) {
    const float* mapping = (const float*)d_in[0];
    const float* D       = (const float*)d_in[1];
    float* out = (float*)d_out;

    unsigned short* buf2 = (unsigned short*)d_ws;        // 2 MiB
    float* sq            = (float*)(buf2 + NN * DIM);    // NN floats
    float* partials      = sq + NN;                      // NBLK floats

    pack_kernel<<<512, 256, 0, stream>>>(mapping, buf2);
    sq_kernel<<<NN / 256, 256, 0, stream>>>(mapping, sq);
    dist_kernel<<<NBLK, 512, 0, stream>>>(buf2, D, sq, partials);
    reduce_kernel<<<1, 256, 0, stream>>>(partials, out);
}